// Round 25
// baseline (54.983 us; speedup 1.0000x reference)
//
#include <hip/hip_runtime.h>
#include <stdint.h>

// Problem constants (match reference)
#define BB 4
#define NN 16384
#define SS 4096
#define CC 64
#define KK 32

// 14-bit quantization (q = rintf(v*16383.f)); d2i exact int.
// Band +-27K around T (2.3x error margin) -> f64 recheck (proven R18..R21).
#define T_INT    10736108
#define LOW_INT  10709108
#define BAND_W   54000

// ws layout:
//   [0, 1MB)      packed float4 {x,y,z,0}
//   [1MB, 1.5MB)  qpts ushort4 {qx,qy,qz,0} (14-bit)
//   [3MB, 11MB)   featB bf16 [B][N][64] (128B rows)
#define PACKED_BYTES ((size_t)BB * NN * sizeof(float4))
#define IDX_BYTES    ((size_t)BB * SS * KK * sizeof(int))

typedef short short2v __attribute__((ext_vector_type(2)));

static __device__ __forceinline__ int mbcnt64(unsigned long long m) {
    return (int)__builtin_amdgcn_mbcnt_hi((unsigned)(m >> 32),
               __builtin_amdgcn_mbcnt_lo((unsigned)m, 0u));
}

#if __has_builtin(__builtin_amdgcn_sdot2)
static __device__ __forceinline__ int dot2i(short2v a, short2v b, int c) {
    return __builtin_amdgcn_sdot2(a, b, c, false);
}
#else
static __device__ __forceinline__ int dot2i(short2v a, short2v b, int c) {
    return (int)a.x * (int)b.x + (int)a.y * (int)b.y + c;   // bit-exact fallback
}
#endif

static __device__ __forceinline__ unsigned short f2bf(float f) {   // RNE
    unsigned u = __builtin_bit_cast(unsigned, f);
    return (unsigned short)((u + 0x7FFFu + ((u >> 16) & 1u)) >> 16);
}
static __device__ __forceinline__ float bf_lo(unsigned w) {
    return __builtin_bit_cast(float, w << 16);
}
static __device__ __forceinline__ float bf_hi(unsigned w) {
    return __builtin_bit_cast(float, w & 0xFFFF0000u);
}

// ---------------------------------------------------------------------------
// Kernel 0: prep = pack+quantize (blocks 0..63) + bf16 transpose (64..1087).
// ---------------------------------------------------------------------------
__global__ __launch_bounds__(256) void prep_kernel(const float* __restrict__ xyz,
                                                   const float* __restrict__ features,
                                                   float4* __restrict__ packed,
                                                   ushort4* __restrict__ qpts,
                                                   unsigned short* __restrict__ featB) {
    int blk = blockIdx.x;
    if (blk < 64) {
        for (int i = 0; i < 4; ++i) {
            int p = blk * 1024 + i * 256 + (int)threadIdx.x;
            float x = xyz[(size_t)p * 3 + 0];
            float y = xyz[(size_t)p * 3 + 1];
            float z = xyz[(size_t)p * 3 + 2];
            packed[p] = make_float4(x, y, z, 0.0f);
            ushort4 q;
            q.x = (unsigned short)rintf(x * 16383.0f);
            q.y = (unsigned short)rintf(y * 16383.0f);
            q.z = (unsigned short)rintf(z * 16383.0f);
            q.w = 0;
            qpts[p] = q;
        }
        return;
    }
    blk -= 64;
    int b  = blk >> 8;
    int n0 = (blk & 255) << 6;
    const float* f = features + (size_t)b * CC * NN;
    for (int i = 0; i < 4; ++i) {
        int e  = (int)threadIdx.x + i * 256;   // 0..1023
        int c4 = e & 15;
        int n  = n0 + (e >> 4);
        ushort4 v;
        v.x = f2bf(f[(size_t)(c4 * 4 + 0) * NN + n]);
        v.y = f2bf(f[(size_t)(c4 * 4 + 1) * NN + n]);
        v.z = f2bf(f[(size_t)(c4 * 4 + 2) * NN + n]);
        v.w = f2bf(f[(size_t)(c4 * 4 + 3) * NN + n]);
        *(ushort4*)(featB + ((size_t)b * NN + n) * 64 + c4 * 4) = v;   // 8B store
    }
}

// ---------------------------------------------------------------------------
// Kernel 1 (fused v25 = v23 with CORRECT swizzle + decode for 1024 blocks):
//   grid = 1024 blocks; wgid = (bid&7)*128 + (bid>>3)   [bijective: 1024%8==0]
//   b = wgid>>8 in [0,4); sbase = (wgid&255)<<4 in [0,4096).
// Per quad: v20's proven scan -> barrier -> xyz writes + stage 128 bf16 rows
// (16KB) -> barrier -> feature writes LAST, no trailing barrier (stores
// drain under next quad's scan; 4x fewer endpgm drains).
// ---------------------------------------------------------------------------
__global__ __launch_bounds__(256) void fused_kernel(const float4* __restrict__ packed,
                                                    const ushort4* __restrict__ qpts,
                                                    const float* __restrict__ new_xyz,
                                                    const unsigned short* __restrict__ featB,
                                                    float* __restrict__ out) {
    __shared__ int   sidx[128];          // [cl*32 + slot], cl = centroid in quad
    __shared__ float snc[12];
    __shared__ uint4 sfeat[128][8];      // 16KB; col = (c8 + row) & 7

    int bid  = (int)blockIdx.x;
    int wgid = (bid & 7) * 128 + (bid >> 3);   // bijective for 1024 blocks
    int b     = wgid >> 8;                     // 0..3
    int sbase = (wgid & 255) << 4;             // 0..4080
    int t  = (int)threadIdx.x;
    int w = t >> 6, lane = t & 63;

    const float4* pts = packed + (size_t)b * NN;
    const uint4*  qv  = (const uint4*)(qpts + (size_t)b * NN);  // 2 pts / uint4
    const size_t cs = (size_t)SS * KK;

    for (int g = 0; g < 4; ++g) {
        int s0 = sbase + g * 4;
        int s  = s0 + w;                 // this wave's centroid

        if (t < 12) snc[t] = new_xyz[((size_t)(b * SS + s0 + t / 3)) * 3 + (t % 3)];

        const float* nc = new_xyz + (size_t)(b * SS + s) * 3;
        const float nxf = nc[0], nyf = nc[1], nzf = nc[2];
        const int qcx = (int)rintf(nxf * 16383.0f);
        const int qcy = (int)rintf(nyf * 16383.0f);
        const int qcz = (int)rintf(nzf * 16383.0f);
        const short2v cxy2 = __builtin_bit_cast(short2v,
                                (unsigned)((qcy << 16) | (qcx & 0xFFFF)));
        const short2v cz2  = __builtin_bit_cast(short2v, (unsigned)qcz);
        const double nx = (double)nxf, ny = (double)nyf, nz = (double)nzf;
        const double t1 = nx * nx + ny * ny + nz * nz;
        const double r2 = 0.2 * 0.2;

#define TESTQ(WXY, WZ, J, INB)                                                  \
    {                                                                           \
        short2v dxy = __builtin_bit_cast(short2v, (WXY)) - cxy2;                \
        short2v dzv = __builtin_bit_cast(short2v, (WZ))  - cz2;                 \
        int d2i = dot2i(dxy, dxy, dot2i(dzv, dzv, 0));                          \
        if ((unsigned)(d2i - LOW_INT) < (unsigned)BAND_W) {                     \
            float4 p = pts[J];                                                  \
            double pxd = (double)p.x, pyd = (double)p.y, pzd = (double)p.z;     \
            double t2d = pxd * pxd + pyd * pyd + pzd * pzd;                     \
            double dtd = nx * pxd + ny * pyd + nz * pzd;                        \
            INB = ((t1 + t2d) - 2.0 * dtd) < r2;                                \
        } else {                                                                \
            INB = d2i < T_INT;                                                  \
        }                                                                       \
    }

        // ---- Phase A: scan, 4 points/lane/iter, 1-iter prefetch (v20) ----
        int cnt = 0;
        int first = 0;
        uint4 u0 = qv[lane];
        uint4 u1 = qv[64 + lane];
        for (int i = 0; i < NN / 2; i += 128) {
            int nb = (i + 128 < NN / 2) ? (i + 128) : i;
            uint4 p0q = qv[nb + lane];
            uint4 p1q = qv[nb + 64 + lane];
            int base = i * 2;
            int jA = base + 2 * lane;
            int jC = base + 128 + 2 * lane;

            bool iA, iB, iC, iD;
            TESTQ(u0.x, u0.y, jA, iA)
            TESTQ(u0.z, u0.w, jA + 1, iB)
            TESTQ(u1.x, u1.y, jC, iC)
            TESTQ(u1.z, u1.w, jC + 1, iD)

            unsigned long long mA = __ballot(iA);
            unsigned long long mB = __ballot(iB);
            unsigned long long mC = __ballot(iC);
            unsigned long long mD = __ballot(iD);

            if (cnt == 0 && (mA | mB | mC | mD)) {
                if (mA | mB) {
                    int cA = mA ? 2 * (int)__builtin_ctzll(mA)     : 0x7FFFFFFF;
                    int cB = mB ? 2 * (int)__builtin_ctzll(mB) + 1 : 0x7FFFFFFF;
                    first = base + (cA < cB ? cA : cB);
                } else {
                    int cC = mC ? 2 * (int)__builtin_ctzll(mC)     : 0x7FFFFFFF;
                    int cD = mD ? 2 * (int)__builtin_ctzll(mD) + 1 : 0x7FFFFFFF;
                    first = base + 128 + (cC < cD ? cC : cD);
                }
            }
            int preAB = mbcnt64(mA) + mbcnt64(mB);
            int cAB   = (int)__popcll(mA) + (int)__popcll(mB);
            int preCD = mbcnt64(mC) + mbcnt64(mD);
            if (iA) { int sl = cnt + preAB;                      if (sl < KK) sidx[w * KK + sl] = jA; }
            if (iB) { int sl = cnt + preAB + (iA ? 1 : 0);       if (sl < KK) sidx[w * KK + sl] = jA + 1; }
            if (iC) { int sl = cnt + cAB + preCD;                if (sl < KK) sidx[w * KK + sl] = jC; }
            if (iD) { int sl = cnt + cAB + preCD + (iC ? 1 : 0); if (sl < KK) sidx[w * KK + sl] = jC + 1; }
            cnt += cAB + (int)__popcll(mC) + (int)__popcll(mD);
            if (cnt >= KK) break;
            u0 = p0q; u1 = p1q;
        }
#undef TESTQ
        if (lane >= cnt && lane < KK) sidx[w * KK + lane] = first;   // fill
        __syncthreads();                 // barrier1: sidx + snc ready

        size_t obase = (size_t)(b * 67) * cs + (size_t)s0 * KK;

        // ---- B0: xyz channels (t<128 = 4 centroids x 32 slots) ----
        if (t < 128) {
            int cl = t >> 5, k = t & 31;
            float4 p = pts[sidx[t]];
            size_t o = obase + (size_t)cl * KK + k;
            out[o]          = p.x - snc[cl * 3 + 0];
            out[o + cs]     = p.y - snc[cl * 3 + 1];
            out[o + 2 * cs] = p.z - snc[cl * 3 + 2];
        }
        // ---- stage all 128 bf16 rows (16KB), swizzled ----
        {
            int row = t >> 1;            // 0..127, 2 threads/row
            int q   = t & 1;             // 64B half of the 128B row
            const uint4* src = (const uint4*)(featB +
                ((size_t)b * NN + sidx[row]) * 64) + q * 4;
#pragma unroll
            for (int j = 0; j < 4; ++j)
                sfeat[row][(q * 4 + j + row) & 7] = src[j];
        }
        __syncthreads();                 // barrier2: sfeat ready

        // ---- feature writes LAST (no trailing barrier; stores drain
        //      under the next quad's scan) ----
#pragma unroll
        for (int cc = 0; cc < 2; ++cc) {
            int c8 = w * 2 + cc;                        // wave-uniform 0..7
            int col = (c8 + lane) & 7;
            uint4 v0 = sfeat[lane][col];                // ds_read_b128
            uint4 v1 = sfeat[64 + lane][col];
            float* pl = out + obase + (size_t)(3 + c8 * 8) * cs + lane;
            pl[0]           = bf_lo(v0.x);  pl[64]          = bf_lo(v1.x);
            pl[cs]          = bf_hi(v0.x);  pl[cs + 64]     = bf_hi(v1.x);
            pl[2 * cs]      = bf_lo(v0.y);  pl[2 * cs + 64] = bf_lo(v1.y);
            pl[3 * cs]      = bf_hi(v0.y);  pl[3 * cs + 64] = bf_hi(v1.y);
            pl[4 * cs]      = bf_lo(v0.z);  pl[4 * cs + 64] = bf_lo(v1.z);
            pl[5 * cs]      = bf_hi(v0.z);  pl[5 * cs + 64] = bf_hi(v1.z);
            pl[6 * cs]      = bf_lo(v0.w);  pl[6 * cs + 64] = bf_lo(v1.w);
            pl[7 * cs]      = bf_hi(v0.w);  pl[7 * cs + 64] = bf_hi(v1.w);
        }
    }
}

extern "C" void kernel_launch(void* const* d_in, const int* in_sizes, int n_in,
                              void* d_out, int out_size, void* d_ws, size_t ws_size,
                              hipStream_t stream) {
    const float* xyz      = (const float*)d_in[0];   // [B,N,3]
    const float* new_xyz  = (const float*)d_in[1];   // [B,S,3]
    const float* features = (const float*)d_in[2];   // [B,C,N]
    float* out = (float*)d_out;                      // [B,67,S,K]

    float4*         packed = (float4*)d_ws;
    ushort4*        qpts   = (ushort4*)((char*)d_ws + PACKED_BYTES);
    unsigned short* featB  = (unsigned short*)((char*)d_ws + PACKED_BYTES + IDX_BYTES);

    prep_kernel<<<64 + BB * (NN / 64), 256, 0, stream>>>(xyz, features, packed,
                                                         qpts, featB);
    fused_kernel<<<BB * SS / 16, 256, 0, stream>>>(packed, qpts, new_xyz, featB, out);
}

// Round 26
// 45.725 us; speedup vs baseline: 1.2025x; 1.2025x over previous
//
#include <hip/hip_runtime.h>
#include <stdint.h>

// Problem constants (match reference)
#define BB 4
#define NN 16384
#define SS 4096
#define CC 64
#define KK 32

// 14-bit quantization (q = rintf(v*16383.f)); d2i exact int.
// Band +-27K around T (2.3x error margin) -> f64 recheck (proven R18..R21).
#define T_INT    10736108
#define LOW_INT  10709108
#define BAND_W   54000

// ws layout:
//   [0, 1MB)      packed float4 {x,y,z,0}
//   [1MB, 1.5MB)  qpts ushort4 {qx,qy,qz,0} (14-bit)
//   [3MB, 11MB)   featB bf16 [B][N][64] (128B rows)
#define PACKED_BYTES ((size_t)BB * NN * sizeof(float4))
#define IDX_BYTES    ((size_t)BB * SS * KK * sizeof(int))

typedef short short2v __attribute__((ext_vector_type(2)));

static __device__ __forceinline__ int mbcnt64(unsigned long long m) {
    return (int)__builtin_amdgcn_mbcnt_hi((unsigned)(m >> 32),
               __builtin_amdgcn_mbcnt_lo((unsigned)m, 0u));
}

#if __has_builtin(__builtin_amdgcn_sdot2)
static __device__ __forceinline__ int dot2i(short2v a, short2v b, int c) {
    return __builtin_amdgcn_sdot2(a, b, c, false);
}
#else
static __device__ __forceinline__ int dot2i(short2v a, short2v b, int c) {
    return (int)a.x * (int)b.x + (int)a.y * (int)b.y + c;   // bit-exact fallback
}
#endif

static __device__ __forceinline__ unsigned short f2bf(float f) {   // RNE
    unsigned u = __builtin_bit_cast(unsigned, f);
    return (unsigned short)((u + 0x7FFFu + ((u >> 16) & 1u)) >> 16);
}
static __device__ __forceinline__ float bf_lo(unsigned w) {
    return __builtin_bit_cast(float, w << 16);
}
static __device__ __forceinline__ float bf_hi(unsigned w) {
    return __builtin_bit_cast(float, w & 0xFFFF0000u);
}

// ---------------------------------------------------------------------------
// Kernel 0: prep = pack+quantize (blocks 0..63) + bf16 transpose (64..1087).
// ---------------------------------------------------------------------------
__global__ __launch_bounds__(256) void prep_kernel(const float* __restrict__ xyz,
                                                   const float* __restrict__ features,
                                                   float4* __restrict__ packed,
                                                   ushort4* __restrict__ qpts,
                                                   unsigned short* __restrict__ featB) {
    int blk = blockIdx.x;
    if (blk < 64) {
        for (int i = 0; i < 4; ++i) {
            int p = blk * 1024 + i * 256 + (int)threadIdx.x;
            float x = xyz[(size_t)p * 3 + 0];
            float y = xyz[(size_t)p * 3 + 1];
            float z = xyz[(size_t)p * 3 + 2];
            packed[p] = make_float4(x, y, z, 0.0f);
            ushort4 q;
            q.x = (unsigned short)rintf(x * 16383.0f);
            q.y = (unsigned short)rintf(y * 16383.0f);
            q.z = (unsigned short)rintf(z * 16383.0f);
            q.w = 0;
            qpts[p] = q;
        }
        return;
    }
    blk -= 64;
    int b  = blk >> 8;
    int n0 = (blk & 255) << 6;
    const float* f = features + (size_t)b * CC * NN;
    for (int i = 0; i < 4; ++i) {
        int e  = (int)threadIdx.x + i * 256;   // 0..1023
        int c4 = e & 15;
        int n  = n0 + (e >> 4);
        ushort4 v;
        v.x = f2bf(f[(size_t)(c4 * 4 + 0) * NN + n]);
        v.y = f2bf(f[(size_t)(c4 * 4 + 1) * NN + n]);
        v.z = f2bf(f[(size_t)(c4 * 4 + 2) * NN + n]);
        v.w = f2bf(f[(size_t)(c4 * 4 + 3) * NN + n]);
        *(ushort4*)(featB + ((size_t)b * NN + n) * 64 + c4 * 4) = v;   // 8B store
    }
}

// ---------------------------------------------------------------------------
// Kernel 1 (fused v20 re-land — measured best, R20: 45.76us, absmax 0.0):
// 4-wave block, 4 centroids; scan = 4 pts/lane/iter (R18-validated ordering)
// with packed-i16 math (R19); band -> f64 recheck (bit-identical decisions).
// Phase B = v15 structure on bf16 rows (8KB LDS).
// ---------------------------------------------------------------------------
__global__ __launch_bounds__(256) void fused_kernel(const float4* __restrict__ packed,
                                                    const ushort4* __restrict__ qpts,
                                                    const float* __restrict__ new_xyz,
                                                    const unsigned short* __restrict__ featB,
                                                    float* __restrict__ out) {
    __shared__ int   sidx[128];
    __shared__ float snc[12];
    __shared__ uint4 sfeat[64][8];     // 8KB; col = (c8 + row) & 7

    int bid  = (int)blockIdx.x;
    int wgid = (bid & 7) * 512 + (bid >> 3);   // bijective: 4096 % 8 == 0
    int b  = wgid >> 10;
    int s0 = (wgid & 1023) << 2;
    int t  = (int)threadIdx.x;
    int w = t >> 6, lane = t & 63;
    int s = s0 + w;

    if (t < 12) snc[t] = new_xyz[((size_t)(b * SS + s0 + t / 3)) * 3 + (t % 3)];

    const float* nc = new_xyz + (size_t)(b * SS + s) * 3;
    const float nxf = nc[0], nyf = nc[1], nzf = nc[2];
    const int qcx = (int)rintf(nxf * 16383.0f);
    const int qcy = (int)rintf(nyf * 16383.0f);
    const int qcz = (int)rintf(nzf * 16383.0f);
    const short2v cxy2 = __builtin_bit_cast(short2v, (unsigned)((qcy << 16) | (qcx & 0xFFFF)));
    const short2v cz2  = __builtin_bit_cast(short2v, (unsigned)qcz);
    const double nx = (double)nxf, ny = (double)nyf, nz = (double)nzf;
    const double t1 = nx * nx + ny * ny + nz * nz;
    const double r2 = 0.2 * 0.2;

    const float4* pts = packed + (size_t)b * NN;
    const uint4*  qv  = (const uint4*)(qpts + (size_t)b * NN);  // 2 pts / uint4

#define TESTQ(WXY, WZ, J, INB)                                                  \
    {                                                                           \
        short2v dxy = __builtin_bit_cast(short2v, (WXY)) - cxy2;                \
        short2v dz2v = __builtin_bit_cast(short2v, (WZ)) - cz2;                 \
        int d2i = dot2i(dxy, dxy, dot2i(dz2v, dz2v, 0));                        \
        if ((unsigned)(d2i - LOW_INT) < (unsigned)BAND_W) {                     \
            float4 p = pts[J];                                                  \
            double pxd = (double)p.x, pyd = (double)p.y, pzd = (double)p.z;     \
            double t2d = pxd * pxd + pyd * pyd + pzd * pzd;                     \
            double dtd = nx * pxd + ny * pyd + nz * pzd;                        \
            INB = ((t1 + t2d) - 2.0 * dtd) < r2;                                \
        } else {                                                                \
            INB = d2i < T_INT;                                                  \
        }                                                                       \
    }

    // ---- Phase A: scan, 4 points/lane/iter, 1-iter prefetch ----
    int cnt = 0;
    int first = 0;
    uint4 u0 = qv[lane];
    uint4 u1 = qv[64 + lane];
    for (int i = 0; i < NN / 2; i += 128) {
        int nb = (i + 128 < NN / 2) ? (i + 128) : i;
        uint4 n0 = qv[nb + lane];
        uint4 n1 = qv[nb + 64 + lane];
        int base = i * 2;
        int jA = base + 2 * lane;
        int jC = base + 128 + 2 * lane;

        bool iA, iB, iC, iD;
        TESTQ(u0.x, u0.y, jA, iA)
        TESTQ(u0.z, u0.w, jA + 1, iB)
        TESTQ(u1.x, u1.y, jC, iC)
        TESTQ(u1.z, u1.w, jC + 1, iD)

        unsigned long long mA = __ballot(iA);
        unsigned long long mB = __ballot(iB);
        unsigned long long mC = __ballot(iC);
        unsigned long long mD = __ballot(iD);

        if (cnt == 0 && (mA | mB | mC | mD)) {
            if (mA | mB) {
                int cA = mA ? 2 * (int)__builtin_ctzll(mA)     : 0x7FFFFFFF;
                int cB = mB ? 2 * (int)__builtin_ctzll(mB) + 1 : 0x7FFFFFFF;
                first = base + (cA < cB ? cA : cB);
            } else {
                int cC = mC ? 2 * (int)__builtin_ctzll(mC)     : 0x7FFFFFFF;
                int cD = mD ? 2 * (int)__builtin_ctzll(mD) + 1 : 0x7FFFFFFF;
                first = base + 128 + (cC < cD ? cC : cD);
            }
        }
        int preAB = mbcnt64(mA) + mbcnt64(mB);
        int cAB   = (int)__popcll(mA) + (int)__popcll(mB);
        int preCD = mbcnt64(mC) + mbcnt64(mD);
        if (iA) { int sl = cnt + preAB;                      if (sl < KK) sidx[w * KK + sl] = jA; }
        if (iB) { int sl = cnt + preAB + (iA ? 1 : 0);       if (sl < KK) sidx[w * KK + sl] = jA + 1; }
        if (iC) { int sl = cnt + cAB + preCD;                if (sl < KK) sidx[w * KK + sl] = jC; }
        if (iD) { int sl = cnt + cAB + preCD + (iC ? 1 : 0); if (sl < KK) sidx[w * KK + sl] = jC + 1; }
        cnt += cAB + (int)__popcll(mC) + (int)__popcll(mD);
        if (cnt >= KK) break;
        u0 = n0; u1 = n1;
    }
#undef TESTQ
    if (lane >= cnt && lane < KK) sidx[w * KK + lane] = first;   // fill (0 if none)
    __syncthreads();

    // ---- Phase B0: xyz channels via packed gathers (exact f32) ----
    const size_t cs = (size_t)SS * KK;
    size_t obase = (size_t)(b * 67) * cs + (size_t)s0 * KK;
    if (t < 128) {
        int cl = t >> 5, k = t & 31;
        float4 p = pts[sidx[t]];
        size_t o = obase + (size_t)cl * KK + k;
        out[o]          = p.x - snc[cl * 3 + 0];
        out[o + cs]     = p.y - snc[cl * 3 + 1];
        out[o + 2 * cs] = p.z - snc[cl * 3 + 2];
    }

    // ---- Phase B: stage bf16 rows + write, 2 centroids per pass ----
    for (int pass = 0; pass < 2; ++pass) {
        {
            int rl = t >> 2;                 // 64 rows, 4 threads/row
            int q  = t & 3;
            const uint4* src = (const uint4*)(featB +
                ((size_t)b * NN + sidx[pass * 64 + rl]) * 64);
            sfeat[rl][(q * 2     + rl) & 7] = src[q * 2];
            sfeat[rl][(q * 2 + 1 + rl) & 7] = src[q * 2 + 1];
        }
        __syncthreads();

        float* pbase = out + obase + (size_t)pass * 64;
        for (int cc = 0; cc < 2; ++cc) {
            int c8 = w * 2 + cc;                        // wave-uniform 0..7
            uint4 v = sfeat[lane][(c8 + lane) & 7];     // one ds_read_b128 = 8 bf16
            float* pl = pbase + lane;
            size_t cb = (size_t)(3 + c8 * 8) * cs;
            pl[cb]          = bf_lo(v.x);
            pl[cb + cs]     = bf_hi(v.x);
            pl[cb + 2 * cs] = bf_lo(v.y);
            pl[cb + 3 * cs] = bf_hi(v.y);
            pl[cb + 4 * cs] = bf_lo(v.z);
            pl[cb + 5 * cs] = bf_hi(v.z);
            pl[cb + 6 * cs] = bf_lo(v.w);
            pl[cb + 7 * cs] = bf_hi(v.w);
        }
        __syncthreads();   // before sfeat reuse
    }
}

extern "C" void kernel_launch(void* const* d_in, const int* in_sizes, int n_in,
                              void* d_out, int out_size, void* d_ws, size_t ws_size,
                              hipStream_t stream) {
    const float* xyz      = (const float*)d_in[0];   // [B,N,3]
    const float* new_xyz  = (const float*)d_in[1];   // [B,S,3]
    const float* features = (const float*)d_in[2];   // [B,C,N]
    float* out = (float*)d_out;                      // [B,67,S,K]

    float4*         packed = (float4*)d_ws;
    ushort4*        qpts   = (ushort4*)((char*)d_ws + PACKED_BYTES);
    unsigned short* featB  = (unsigned short*)((char*)d_ws + PACKED_BYTES + IDX_BYTES);

    prep_kernel<<<64 + BB * (NN / 64), 256, 0, stream>>>(xyz, features, packed,
                                                         qpts, featB);
    fused_kernel<<<BB * SS / 4, 256, 0, stream>>>(packed, qpts, new_xyz, featB, out);
}